// Round 5
// baseline (257.540 us; speedup 1.0000x reference)
//
#include <hip/hip_runtime.h>
#include <stdint.h>

// FactorLayer: B=4096, D=4096, T=16, float32.
// X = znorm(inputs); Y = X@W_static; Z = X@W; sequential deflation collapses
// to 17-dim recurrences on the Gram of [Y|Z|1]; Out = Z - [Y|1]@Wmat.
// Structure (R16): memset + 2 launches, atomics-only cross-block handoffs
// (R14-proven; R12 proved plain-store handoff = buffer_wbl2 disaster).
// kAB: input read ONCE. Each block loads its 64x128 fragment to REGISTERS
// (8 float4 = 32 VGPR; R15 BUG: stats+stage loops weren't unrolled ->
// runtime-indexed f0[s] went to SCRATCH, VGPR=28, 141us. Fix: #pragma unroll
// on BOTH loops -> static indices). Stats partials atomicAdd'ed in DOUBLE
// (native f64 atomics; order-independent at fp32 precision -> absmax back
// from 1.0 to ~0.25). counter[dg] spin until all 64 rowgroups arrive (2048
// blocks = exact 8/CU x 256 CU residency), then inv + GEMM from registers.
// kCE: per-block ypart reduce + gram atomicAdd + 64-block spin + solve (R14).
// Journal: R3 coop no-op. R7 readfirstlane weight s_load. R12 threadfence
// FAIL (+313us). R13 16-dgroup FAIL (occupancy). R14 kCE fuse WIN (-3us).
// R15 scratch-spill FAIL (+109us, rule #20). Fixed harness cost ~110us.

#define BB 4096
#define DD 4096
#define EPSF 1e-6f

// ws layout (float indices)
#define O_SUMD    0u          // double colsum[4096] (8192 float slots)
#define O_SQD     8192u       // double colsq[4096]
#define O_GRAMM   16384u      // 8 copies x 1120 (33x33, upper-tri used)
#define O_CNTDG   25344u      // 32 uint32 dgroup arrival counters
#define O_CNTF    25376u      // 1 uint32 final barrier counter
#define ZERO_BYTES (25377u * 4u)
#define O_YPART   25600u      // [32 dgroups][4096][32] (16B-aligned)

__device__ __forceinline__ int gidx(int a, int b) {   // upper-tri gram index
    int lo = a < b ? a : b, hi = a < b ? b : a;
    return lo * 33 + hi;
}

__device__ __forceinline__ float agl(const float* p) { // coherent-point load
    unsigned int u = __hip_atomic_load((const unsigned int*)p,
                                       __ATOMIC_RELAXED, __HIP_MEMORY_SCOPE_AGENT);
    return __uint_as_float(u);
}

__device__ __forceinline__ double agl64(const double* p) {
    unsigned long long u = __hip_atomic_load((const unsigned long long*)p,
                                             __ATOMIC_RELAXED, __HIP_MEMORY_SCOPE_AGENT);
    return __longlong_as_double((long long)u);
}

// ====== kAB: fragment->regs, stats+spin, inv, GEMM R = (in.inv) @ Wcat ======
// 2048 blocks = 32 dgroups(128 d) x 64 rowgroups(64 rows). 8 blocks/CU exact.
__global__ __launch_bounds__(256, 8)
void kAB(const float* __restrict__ in, const float* __restrict__ W,
         const float* __restrict__ Wstat, float* __restrict__ ws,
         float* __restrict__ ypart) {
    __shared__ __align__(16) float tile[64 * 33];     // 8448 B; stats bufs union
    __shared__ __align__(16) float inv_s[128];
    int b = blockIdx.x, t = threadIdx.x;
    int dg = b & 31, rg = b >> 5;
    int dbase = dg * 128, rowbase = rg * 64;
    int chunk = t & 7, srow = t >> 3;                 // staging role (srow<32)
    int row = t & 63;
    int jq = __builtin_amdgcn_readfirstlane(t >> 6);  // wave-uniform -> s_load
    const float* inp = in + (size_t)(rowbase + srow) * DD + dbase + chunk * 4;

    // load entire 64x128 fragment into registers (8 x float4 = 32 VGPR)
    float4 f0[4], f1[4];
    #pragma unroll
    for (int s = 0; s < 4; ++s) {
        f0[s] = *(const float4*)(inp + s * 32);
        f1[s] = *(const float4*)(inp + (size_t)32 * DD + s * 32);
    }

    // stats: 4 rounds through LDS; DOUBLE atomicAdd globals (order-indep).
    // MUST be unrolled: f0[s]/f1[s] static-indexed (rule #20, R15 lesson).
    double* dsum = (double*)(ws + O_SUMD);
    double* dsq  = (double*)(ws + O_SQD);
    float* sbuf = tile;                               // 32*33 floats
    float* qbuf = tile + 1056;                        // 32*33 floats
    #pragma unroll
    for (int s = 0; s < 4; ++s) {
        float4 a = f0[s], c = f1[s];
        int lb = srow * 33 + chunk * 4;
        sbuf[lb+0] = a.x + c.x; qbuf[lb+0] = a.x*a.x + c.x*c.x;
        sbuf[lb+1] = a.y + c.y; qbuf[lb+1] = a.y*a.y + c.y*c.y;
        sbuf[lb+2] = a.z + c.z; qbuf[lb+2] = a.z*a.z + c.z*c.z;
        sbuf[lb+3] = a.w + c.w; qbuf[lb+3] = a.w*a.w + c.w*c.w;
        __syncthreads();
        if (t < 64) {                                 // 1 wave: 32 sums + 32 sqs
            int col = t & 31;
            const float* bufp = (t >= 32) ? qbuf : sbuf;
            float acc = 0.f;
            #pragma unroll
            for (int r = 0; r < 32; ++r) acc += bufp[r * 33 + col];
            double* dstp = (t >= 32) ? dsq : dsum;
            atomicAdd(&dstp[dbase + s * 32 + col], (double)acc);
        }
        __syncthreads();
    }

    // arrival + spin: need all 64 rowgroups of this dgroup before inv.
    // syncthreads above drained vmcnt -> stat atomics at coherent point.
    unsigned int* cdg = (unsigned int*)(ws + O_CNTDG);
    if (t == 0) {
        atomicAdd(&cdg[dg], 1u);
        while (__hip_atomic_load(&cdg[dg], __ATOMIC_RELAXED,
                                 __HIP_MEMORY_SCOPE_AGENT) < 64u)
            __builtin_amdgcn_s_sleep(2);
    }
    __syncthreads();

    if (t < 128) {                                    // inv via coherent loads
        double s = agl64(&dsum[dbase + t]);
        double q = agl64(&dsq[dbase + t]);
        float m = (float)(s * (1.0 / BB));
        float var = (float)(q * (1.0 / BB)) - m * m; if (var < 0.f) var = 0.f;
        inv_s[t] = 1.0f / (sqrtf(var) + EPSF);
    }
    __syncthreads();

    // GEMM: identical stage loop, sourced from register fragment.
    // MUST be unrolled: f0[stage] static-indexed (rule #20, R15 lesson).
    float acc[8];
    #pragma unroll
    for (int i = 0; i < 8; ++i) acc[i] = 0.f;
    const float* wbase = (jq < 2) ? (Wstat + jq * 8) : (W + (jq - 2) * 8);
    #pragma unroll
    for (int stage = 0; stage < 4; ++stage) {
        int ds0 = stage * 32;
        float4 iv4 = *(const float4*)&inv_s[ds0 + chunk * 4];
        float4 a = f0[stage], c = f1[stage];
        int b0 = srow * 33 + chunk * 4;               // scale folded into staging
        tile[b0 + 0] = a.x * iv4.x; tile[b0 + 1] = a.y * iv4.y;
        tile[b0 + 2] = a.z * iv4.z; tile[b0 + 3] = a.w * iv4.w;
        int b1 = (srow + 32) * 33 + chunk * 4;
        tile[b1 + 0] = c.x * iv4.x; tile[b1 + 1] = c.y * iv4.y;
        tile[b1 + 2] = c.z * iv4.z; tile[b1 + 3] = c.w * iv4.w;
        __syncthreads();
        const float* trow = tile + row * 33;
        #pragma unroll 4
        for (int dl = 0; dl < 32; ++dl) {
            float xs = trow[dl];
            const float* wr = wbase + (size_t)(dbase + ds0 + dl) * 16;
            #pragma unroll
            for (int j = 0; j < 8; ++j) acc[j] += xs * wr[j];
        }
        __syncthreads();
    }
    float* dst = ypart + ((size_t)dg * BB + rowbase + row) * 32 + jq * 8;
    *(float4*)(dst + 0) = make_float4(acc[0], acc[1], acc[2], acc[3]);
    *(float4*)(dst + 4) = make_float4(acc[4], acc[5], acc[6], acc[7]);
}

// ====== kCE: per-block ypart reduce + gram atomics + spin + solve ===========
// 64 blocks x 512 threads, all co-resident (64 <= 256 CUs). Atomics-only
// cross-block communication; no global yz; no fences.
__global__ __launch_bounds__(512, 1)
void kCE(float* __restrict__ ws, float* __restrict__ out) {
    __shared__ __align__(16) float yzs[64 * 36];      // own 64 rows of [Ry|Rz|1]
    __shared__ float Sv[33], GA[17 * 17], gz[17 * 16], v[15][17], gad[15][16],
                     gzd[15][16], gu[17], u[17], st[2], wm[17 * 16];
    int b = blockIdx.x, t = threadIdx.x;
    int rowbase = b * 64;
    const float invB = 1.0f / BB;

    // phase 1: reduce 32 dgroup planes for own rows -> LDS (no global write)
    {
        int r = t >> 3, q = (t & 7) * 4;              // 512 threads = 64 rows x 8 quads
        const float* yp = ws + O_YPART;
        size_t off = (size_t)(rowbase + r) * 32 + q;
        float x0=0.f, x1=0.f, x2=0.f, x3=0.f;
        #pragma unroll 8
        for (int dg = 0; dg < 32; ++dg) {
            float4 vv = *(const float4*)&yp[(size_t)dg * (BB * 32) + off];
            x0 += vv.x; x1 += vv.y; x2 += vv.z; x3 += vv.w;
        }
        int lb = r * 36 + q;
        yzs[lb + 0] = x0; yzs[lb + 1] = x1; yzs[lb + 2] = x2; yzs[lb + 3] = x3;
        if (q == 0) yzs[r * 36 + 32] = 1.0f;          // ones column
    }
    __syncthreads();

    // phase 2: gram contribution for own 64 rows (8-way copies by b&7)
    float* gm8 = ws + O_GRAMM + (size_t)(b & 7) * 1120;
    for (int p = t; p < 561; p += 512) {              // upper-tri pairs i<=j<=32
        int i = 0, rem = p;
        while (rem >= 33 - i) { rem -= 33 - i; ++i; }
        int j = i + rem;
        float a2 = 0.f;
        #pragma unroll 8
        for (int r2 = 0; r2 < 64; ++r2)
            a2 += yzs[r2 * 36 + i] * yzs[r2 * 36 + j];
        atomicAdd(&gm8[i * 33 + j], a2);
    }

    // phase 3: arrival + spin. syncthreads drains vmcnt -> this block's gram
    // atomics are at the coherent point before the counter bump (release).
    __syncthreads();
    unsigned int* cnt = (unsigned int*)(ws + O_CNTF);
    if (t == 0) {
        atomicAdd(cnt, 1u);
        while (__hip_atomic_load(cnt, __ATOMIC_RELAXED,
                                 __HIP_MEMORY_SCOPE_AGENT) < 64u)
            __builtin_amdgcn_s_sleep(8);
    }
    __syncthreads();

    // phase 4: solve, reading gram ONLY via coherent-point atomic loads
    const float* gm = ws + O_GRAMM;
    if (t < 33) {                                     // S_i = <R_i, 1> (i=32: B)
        float s = 0.f;
        #pragma unroll
        for (int m = 0; m < 8; ++m) s += agl(&gm[m * 1120 + gidx(t, 32)]);
        Sv[t] = s;
    }
    __syncthreads();
    for (int idx = t; idx < 17 * 17; idx += 512) {    // centered GA
        int p = idx / 17, q = idx % 17;
        float val;
        if (p < 16 && q < 16) {
            float raw = 0.f;
            #pragma unroll
            for (int m = 0; m < 8; ++m) raw += agl(&gm[m * 1120 + gidx(p, q)]);
            val = raw - Sv[p] * Sv[q] * invB;
        } else if (p == 16 && q == 16) val = (float)BB;
        else val = 0.f;                               // <P,1> = 0 exactly
        GA[idx] = val;
    }
    for (int idx = t; idx < 17 * 16; idx += 512) {    // centered gz
        int p = idx / 16, tt = idx % 16;
        float val = 0.f;
        if (p < 16) {
            float raw = 0.f;
            #pragma unroll
            for (int m = 0; m < 8; ++m) raw += agl(&gm[m * 1120 + gidx(p, 16 + tt)]);
            val = raw - Sv[p] * Sv[16 + tt] * invB;
        }
        gz[idx] = val;
    }
    if (t < 17) u[t] = (t == 0) ? 1.f : 0.f;
    __syncthreads();
    for (int i = 0; i < 15; ++i) {
        if (t < 17) {                                 // gu = GA @ u
            float s = 0.f;
            for (int q = 0; q < 17; ++q) s += GA[t * 17 + q] * u[q];
            gu[t] = s;
        }
        __syncthreads();
        if (t == 0) {                                 // stats of c_i
            float mean = gu[16] * invB, e2 = 0.f;
            for (int p = 0; p < 17; ++p) e2 += u[p] * gu[p];
            e2 *= invB;
            float var = e2 - mean * mean; if (var < 0.f) var = 0.f;
            st[0] = mean; st[1] = 1.0f / (sqrtf(var) + EPSF);
        }
        __syncthreads();
        if (t < 17) v[i][t] = (u[t] - (t == 16 ? st[0] : 0.f)) * st[1];
        __syncthreads();
        if (t < 16) {                                 // conv_i . Y[:,k]
            float s = 0.f;
            for (int p = 0; p < 17; ++p) s += v[i][p] * GA[p * 17 + t];
            gad[i][t] = s;
        } else if (t < 32) {                          // conv_i . Z[:,tt]
            int tt = t - 16;
            float s = 0.f;
            for (int p = 0; p < 17; ++p) s += v[i][p] * gz[p * 16 + tt];
            gzd[i][tt] = s;
        }
        __syncthreads();
        if (t < 17) {                                 // u_{i+1}
            float a2 = 0.f;
            for (int j = 0; j <= i; ++j) a2 += v[j][t] * gad[j][i + 1];
            u[t] = ((t == i + 1) ? 1.f : 0.f) - a2 * invB;
        }
        __syncthreads();
    }
    for (int idx = t; idx < 17 * 16; idx += 512) {
        int p = idx / 16, tt = idx % 16;
        float s = 0.f;
        for (int j = 0; j < tt; ++j) s += v[j][p] * gzd[j][tt];
        wm[idx] = s * invB;
    }
    __syncthreads();
    if (t < 16) {                                     // fold shifts into ones-row
        float adj = Sv[16 + t] * invB;
        for (int p = 0; p < 16; ++p) adj -= Sv[p] * invB * wm[p * 16 + t];
        wm[16 * 16 + t] += adj;
    }
    __syncthreads();
    if (t < 256) {                                    // epilogue: own 64 rows
        int row = t >> 2, c0 = (t & 3) * 4;
        const float* yr = yzs + row * 36;
        float o[4];
        #pragma unroll
        for (int k = 0; k < 4; ++k) o[k] = yr[16 + c0 + k] - wm[16 * 16 + c0 + k];
        #pragma unroll
        for (int p = 0; p < 16; ++p) {
            float yp = yr[p];
            #pragma unroll
            for (int k = 0; k < 4; ++k) o[k] -= yp * wm[p * 16 + c0 + k];
        }
        *(float4*)&out[(size_t)rowbase * 16 + t * 4] = make_float4(o[0], o[1], o[2], o[3]);
    }
}

extern "C" void kernel_launch(void* const* d_in, const int* in_sizes, int n_in,
                              void* d_out, int out_size, void* d_ws, size_t ws_size,
                              hipStream_t stream) {
    const float* in    = (const float*)d_in[0];
    const float* W     = (const float*)d_in[1];
    const float* Wstat = (const float*)d_in[2];
    float* ws  = (float*)d_ws;
    float* out = (float*)d_out;

    hipMemsetAsync(ws, 0, ZERO_BYTES, stream);        // stats + gram + counters
    kAB<<<dim3(2048), dim3(256), 0, stream>>>(in, W, Wstat, ws, ws + O_YPART);
    kCE<<<dim3(64),   dim3(512), 0, stream>>>(ws, out);
}

// Round 6
// 204.198 us; speedup vs baseline: 1.2612x; 1.2612x over previous
//
#include <hip/hip_runtime.h>
#include <stdint.h>

// FactorLayer: B=4096, D=4096, T=16, float32.
// X = znorm(inputs); Y = X@W_static; Z = X@W; sequential deflation collapses
// to 17-dim recurrences on the Gram of [Y|Z|1]; Out = Z - [Y|1]@Wmat.
// Structure (R17): 2 launches. kA: EXACT R14 (stats partials, deterministic;
// zero gram+counters). kBCE: R14 kB GEMM verbatim, then kCE folded in via
// patterns proven cheap at their scale:
//  - ypart written with 8-byte RELAXED AGENT atomic stores (write-through to
//    coherent point; unique addresses -> no RMW contention, ~16.8MB @ BW);
//  - per-rowgroup counter: non-last blocks EXIT (no spin); last arriver
//    reduces its 64 rows via 8-byte agent atomic loads + gram atomicAdd;
//  - only spin = final 64-block counter (R14 kCE-proven scale) before solve.
// R15/R16 lesson: the 2048-block-wide spin structure failed twice with an
// identical unexplained signature (~145us, pipes idle, VGPR=28) -> abandoned.
// Journal: R3 coop no-op. R7 readfirstlane weight s_load. R12 threadfence
// FAIL (+313us). R13 16-dgroup FAIL (occupancy). R14 kCE fuse WIN (146.3).
// R15/R16 kAB fuse FAIL (~255us). Launch gap ~6us. Fixed harness ~110us.

#define BB 4096
#define DD 4096
#define EPSF 1e-6f

// ws layout (float indices)
#define O_PART    0u          // [16 rowgroups][8192]: colsum(0..4095), colsq(4096..8191)
#define O_GRAMM   131072u     // 8 copies x 1120 (33x33, upper-tri used)
#define O_CNTRG   140032u     // 64 uint32 rowgroup arrival counters
#define O_CNTF    140096u     // 1 uint32 final barrier counter
#define O_YPART   140288u     // [32 dgroups][4096][32] (16B-aligned)

__device__ __forceinline__ int gidx(int a, int b) {   // upper-tri gram index
    int lo = a < b ? a : b, hi = a < b ? b : a;
    return lo * 33 + hi;
}

__device__ __forceinline__ float agl(const float* p) { // coherent-point load
    unsigned int u = __hip_atomic_load((const unsigned int*)p,
                                       __ATOMIC_RELAXED, __HIP_MEMORY_SCOPE_AGENT);
    return __uint_as_float(u);
}

__device__ __forceinline__ void ast2(float* p, float a, float b) {
    unsigned long long u = (unsigned long long)__float_as_uint(a)
                         | ((unsigned long long)__float_as_uint(b) << 32);
    __hip_atomic_store((unsigned long long*)p, u,
                       __ATOMIC_RELAXED, __HIP_MEMORY_SCOPE_AGENT);
}

__device__ __forceinline__ void ald2(const float* p, float& a, float& b) {
    unsigned long long u = __hip_atomic_load((const unsigned long long*)p,
                                             __ATOMIC_RELAXED, __HIP_MEMORY_SCOPE_AGENT);
    a = __uint_as_float((unsigned int)u);
    b = __uint_as_float((unsigned int)(u >> 32));
}

// ============ kA: stats partials (16 rowgroups) + zero gram/counters ========
// 512 blocks = 32 colgroups(128 cols) x 16 rowgroups(256 rows).
__global__ __launch_bounds__(256, 2)
void kA(const float* __restrict__ in, float* __restrict__ ws) {
    __shared__ float rs[8 * 132], rq[8 * 132];        // pad 132: avoid 8-way bank hits
    int b = blockIdx.x, t = threadIdx.x;
    int idx = b * 256 + t;
    if (idx < 9216) ws[O_GRAMM + idx] = 0.f;          // 8 gram copies + counters
    int cg = b & 31, rg = b >> 5;
    int dbase = cg * 128, r0 = rg * 256;
    int chunk = t & 31, rr = t >> 5;
    int c0 = dbase + chunk * 4;
    float s0=0.f,s1=0.f,s2=0.f,s3=0.f,q0=0.f,q1=0.f,q2=0.f,q3=0.f;
    #pragma unroll 4
    for (int i = 0; i < 32; ++i) {
        int r = r0 + i * 8 + rr;
        float4 u = *(const float4*)&in[(size_t)r * DD + c0];
        s0 += u.x; q0 += u.x*u.x;  s1 += u.y; q1 += u.y*u.y;
        s2 += u.z; q2 += u.z*u.z;  s3 += u.w; q3 += u.w*u.w;
    }
    int lb = rr * 132 + chunk * 4;
    rs[lb+0]=s0; rs[lb+1]=s1; rs[lb+2]=s2; rs[lb+3]=s3;
    rq[lb+0]=q0; rq[lb+1]=q1; rq[lb+2]=q2; rq[lb+3]=q3;
    __syncthreads();
    float* part = ws + O_PART + (size_t)rg * 8192;
    if (t < 128) {                                    // finalize sums
        float a = 0.f;
        #pragma unroll
        for (int r2 = 0; r2 < 8; ++r2) a += rs[r2 * 132 + t];
        part[dbase + t] = a;
    } else {                                          // finalize sumsqs
        int ci = t - 128;
        float a = 0.f;
        #pragma unroll
        for (int r2 = 0; r2 < 8; ++r2) a += rq[r2 * 132 + ci];
        part[4096 + dbase + ci] = a;
    }
}

// ====== kBCE: R14 kB GEMM + atomic-store ypart + last-arriver kCE tail ======
// 2048 blocks = 32 dgroups(128 d) x 64 rowgroups(64 rows). 8 blocks/CU.
__global__ __launch_bounds__(256, 8)
void kBCE(const float* __restrict__ in, const float* __restrict__ W,
          const float* __restrict__ Wstat, float* __restrict__ ws,
          float* __restrict__ ypart, float* __restrict__ out) {
    // 15.9 KB arena, phase-overlaid:
    //   GEMM phase:  tile[64*33] (0..2111) | inv_s (2112..2239)
    //   tail phase:  yzs[64*36] (0..2303) | solve arrays (2304..3940)
    __shared__ __align__(16) float arena[3968];
    __shared__ int s_last;
    float* tile  = arena;
    float* inv_s = arena + 2112;
    int b = blockIdx.x, t = threadIdx.x;
    int dg = b & 31, rg = b >> 5;
    int dbase = dg * 128, rowbase = rg * 64;
    int chunk = t & 7, srow = t >> 3;                 // staging role (srow<32)
    int row = t & 63;
    int jq = __builtin_amdgcn_readfirstlane(t >> 6);  // wave-uniform -> s_load
    const float* inp = in + (size_t)(rowbase + srow) * DD + dbase + chunk * 4;
    float4 pf0 = *(const float4*)(inp);               // prefetch overlaps prologue
    float4 pf1 = *(const float4*)(inp + (size_t)32 * DD);
    {   // prologue: inv for this block's 128 cols from 16 KB L2-hot partials
        if (t < 128) {
            const float* part = ws + O_PART;
            float s = 0.f, q = 0.f;
            #pragma unroll
            for (int g = 0; g < 16; ++g) {
                s += part[(size_t)g * 8192 + dbase + t];
                q += part[(size_t)g * 8192 + 4096 + dbase + t];
            }
            float m = s * (1.0f / BB);
            float var = q * (1.0f / BB) - m * m; if (var < 0.f) var = 0.f;
            inv_s[t] = 1.0f / (sqrtf(var) + EPSF);
        }
        __syncthreads();
    }
    float acc[8];
    #pragma unroll
    for (int i = 0; i < 8; ++i) acc[i] = 0.f;
    // raw weight base: wave-uniform jq -> scalar loads (R7 lesson)
    const float* wbase = (jq < 2) ? (Wstat + jq * 8) : (W + (jq - 2) * 8);
    for (int stage = 0; stage < 4; ++stage) {
        int ds0 = stage * 32;
        float4 iv4 = *(const float4*)&inv_s[ds0 + chunk * 4];
        int b0 = srow * 33 + chunk * 4;               // scale folded into staging
        tile[b0 + 0] = pf0.x * iv4.x; tile[b0 + 1] = pf0.y * iv4.y;
        tile[b0 + 2] = pf0.z * iv4.z; tile[b0 + 3] = pf0.w * iv4.w;
        int b1 = (srow + 32) * 33 + chunk * 4;
        tile[b1 + 0] = pf1.x * iv4.x; tile[b1 + 1] = pf1.y * iv4.y;
        tile[b1 + 2] = pf1.z * iv4.z; tile[b1 + 3] = pf1.w * iv4.w;
        __syncthreads();
        if (stage < 3) {                              // prefetch next stage
            pf0 = *(const float4*)(inp + (stage + 1) * 32);
            pf1 = *(const float4*)(inp + (size_t)32 * DD + (stage + 1) * 32);
        }
        const float* trow = tile + row * 33;
        #pragma unroll 4
        for (int dl = 0; dl < 32; ++dl) {
            float xs = trow[dl];
            const float* wr = wbase + (size_t)(dbase + ds0 + dl) * 16;
            #pragma unroll
            for (int j = 0; j < 8; ++j) acc[j] += xs * wr[j];
        }
        __syncthreads();
    }
    // epilogue: write-through atomic stores (visible at coherent point)
    float* dst = ypart + ((size_t)dg * BB + rowbase + row) * 32 + jq * 8;
    ast2(dst + 0, acc[0], acc[1]);
    ast2(dst + 2, acc[2], acc[3]);
    ast2(dst + 4, acc[4], acc[5]);
    ast2(dst + 6, acc[6], acc[7]);

    // arrival: barrier drains vmcnt (stores complete) -> counter bump.
    __syncthreads();
    unsigned int* crg = (unsigned int*)(ws + O_CNTRG);
    if (t == 0) s_last = (atomicAdd(&crg[rg], 1u) == 31u);
    __syncthreads();
    if (!s_last) return;                              // non-last: exit, no spin

    // ---------------- last arriver of this rowgroup: kCE tail ----------------
    float* yzs = arena;                               // 64 x 36
    float* Sv  = arena + 2304;                        // 33
    float* GA  = arena + 2337;                        // 289
    float* gz  = arena + 2626;                        // 272
    float* vv_ = arena + 2898;                        // 15*17
    float* gad = arena + 3153;                        // 15*16
    float* gzd = arena + 3393;                        // 15*16
    float* gu  = arena + 3633;                        // 17
    float* u   = arena + 3650;                        // 17
    float* st  = arena + 3667;                        // 2
    float* wm  = arena + 3669;                        // 272
    const float invB = 1.0f / BB;

    // reduce 32 dgroup planes for own 64 rows via coherent 8B atomic loads
    #pragma unroll
    for (int k = 0; k < 2; ++k) {
        int idx = k * 256 + t;                        // 0..511 = 64 rows x 8 quads
        int r = idx >> 3, q = (idx & 7) * 4;
        size_t off = (size_t)(rowbase + r) * 32 + q;
        float x0=0.f, x1=0.f, x2=0.f, x3=0.f;
        #pragma unroll 8
        for (int dg2 = 0; dg2 < 32; ++dg2) {
            const float* p = &ypart[(size_t)dg2 * (BB * 32) + off];
            float a0, a1, a2, a3;
            ald2(p + 0, a0, a1);
            ald2(p + 2, a2, a3);
            x0 += a0; x1 += a1; x2 += a2; x3 += a3;
        }
        int lb = r * 36 + q;
        yzs[lb + 0] = x0; yzs[lb + 1] = x1; yzs[lb + 2] = x2; yzs[lb + 3] = x3;
        if (q == 0) yzs[r * 36 + 32] = 1.0f;          // ones column
    }
    __syncthreads();

    // gram contribution for own 64 rows (8-way copies by rg&7)
    float* gm8 = ws + O_GRAMM + (size_t)(rg & 7) * 1120;
    for (int p = t; p < 561; p += 256) {              // upper-tri pairs i<=j<=32
        int i = 0, rem = p;
        while (rem >= 33 - i) { rem -= 33 - i; ++i; }
        int j = i + rem;
        float a2 = 0.f;
        #pragma unroll 8
        for (int r2 = 0; r2 < 64; ++r2)
            a2 += yzs[r2 * 36 + i] * yzs[r2 * 36 + j];
        atomicAdd(&gm8[i * 33 + j], a2);
    }

    // final barrier: 64 last-arrivers (R14-proven spin scale)
    __syncthreads();
    unsigned int* cnt = (unsigned int*)(ws + O_CNTF);
    if (t == 0) {
        atomicAdd(cnt, 1u);
        while (__hip_atomic_load(cnt, __ATOMIC_RELAXED,
                                 __HIP_MEMORY_SCOPE_AGENT) < 64u)
            __builtin_amdgcn_s_sleep(8);
    }
    __syncthreads();

    // solve, reading gram ONLY via coherent-point atomic loads
    const float* gm = ws + O_GRAMM;
    if (t < 33) {                                     // S_i = <R_i, 1> (i=32: B)
        float s = 0.f;
        #pragma unroll
        for (int m = 0; m < 8; ++m) s += agl(&gm[m * 1120 + gidx(t, 32)]);
        Sv[t] = s;
    }
    __syncthreads();
    for (int idx = t; idx < 17 * 17; idx += 256) {    // centered GA
        int p = idx / 17, q = idx % 17;
        float val;
        if (p < 16 && q < 16) {
            float raw = 0.f;
            #pragma unroll
            for (int m = 0; m < 8; ++m) raw += agl(&gm[m * 1120 + gidx(p, q)]);
            val = raw - Sv[p] * Sv[q] * invB;
        } else if (p == 16 && q == 16) val = (float)BB;
        else val = 0.f;                               // <P,1> = 0 exactly
        GA[idx] = val;
    }
    for (int idx = t; idx < 17 * 16; idx += 256) {    // centered gz
        int p = idx / 16, tt = idx % 16;
        float val = 0.f;
        if (p < 16) {
            float raw = 0.f;
            #pragma unroll
            for (int m = 0; m < 8; ++m) raw += agl(&gm[m * 1120 + gidx(p, 16 + tt)]);
            val = raw - Sv[p] * Sv[16 + tt] * invB;
        }
        gz[idx] = val;
    }
    if (t < 17) u[t] = (t == 0) ? 1.f : 0.f;
    __syncthreads();
    for (int i = 0; i < 15; ++i) {
        if (t < 17) {                                 // gu = GA @ u
            float s = 0.f;
            for (int q = 0; q < 17; ++q) s += GA[t * 17 + q] * u[q];
            gu[t] = s;
        }
        __syncthreads();
        if (t == 0) {                                 // stats of c_i
            float mean = gu[16] * invB, e2 = 0.f;
            for (int p = 0; p < 17; ++p) e2 += u[p] * gu[p];
            e2 *= invB;
            float var = e2 - mean * mean; if (var < 0.f) var = 0.f;
            st[0] = mean; st[1] = 1.0f / (sqrtf(var) + EPSF);
        }
        __syncthreads();
        if (t < 17) vv_[i * 17 + t] = (u[t] - (t == 16 ? st[0] : 0.f)) * st[1];
        __syncthreads();
        if (t < 16) {                                 // conv_i . Y[:,k]
            float s = 0.f;
            for (int p = 0; p < 17; ++p) s += vv_[i * 17 + p] * GA[p * 17 + t];
            gad[i * 16 + t] = s;
        } else if (t < 32) {                          // conv_i . Z[:,tt]
            int tt = t - 16;
            float s = 0.f;
            for (int p = 0; p < 17; ++p) s += vv_[i * 17 + p] * gz[p * 16 + tt];
            gzd[i * 16 + tt] = s;
        }
        __syncthreads();
        if (t < 17) {                                 // u_{i+1}
            float a2 = 0.f;
            for (int j = 0; j <= i; ++j) a2 += vv_[j * 17 + t] * gad[j * 16 + i + 1];
            u[t] = ((t == i + 1) ? 1.f : 0.f) - a2 * invB;
        }
        __syncthreads();
    }
    for (int idx = t; idx < 17 * 16; idx += 256) {
        int p = idx / 16, tt = idx % 16;
        float s = 0.f;
        for (int j = 0; j < tt; ++j) s += vv_[j * 17 + p] * gzd[j * 16 + tt];
        wm[idx] = s * invB;
    }
    __syncthreads();
    if (t < 16) {                                     // fold shifts into ones-row
        float adj = Sv[16 + t] * invB;
        for (int p = 0; p < 16; ++p) adj -= Sv[p] * invB * wm[p * 16 + t];
        wm[16 * 16 + t] += adj;
    }
    __syncthreads();
    {                                                 // epilogue: own 64 rows
        int r = t >> 2, c0 = (t & 3) * 4;
        const float* yr = yzs + r * 36;
        float o[4];
        #pragma unroll
        for (int k = 0; k < 4; ++k) o[k] = yr[16 + c0 + k] - wm[16 * 16 + c0 + k];
        #pragma unroll
        for (int p = 0; p < 16; ++p) {
            float yp = yr[p];
            #pragma unroll
            for (int k = 0; k < 4; ++k) o[k] -= yp * wm[p * 16 + c0 + k];
        }
        *(float4*)&out[(size_t)rowbase * 16 + t * 4] = make_float4(o[0], o[1], o[2], o[3]);
    }
}

extern "C" void kernel_launch(void* const* d_in, const int* in_sizes, int n_in,
                              void* d_out, int out_size, void* d_ws, size_t ws_size,
                              hipStream_t stream) {
    const float* in    = (const float*)d_in[0];
    const float* W     = (const float*)d_in[1];
    const float* Wstat = (const float*)d_in[2];
    float* ws  = (float*)d_ws;
    float* out = (float*)d_out;

    kA<<<dim3(512),   dim3(256), 0, stream>>>(in, ws);
    kBCE<<<dim3(2048), dim3(256), 0, stream>>>(in, W, Wstat, ws, ws + O_YPART, out);
}

// Round 7
// 147.414 us; speedup vs baseline: 1.7471x; 1.3852x over previous
//
#include <hip/hip_runtime.h>
#include <stdint.h>

// FactorLayer: B=4096, D=4096, T=16, float32.
// X = znorm(inputs); Y = X@W_static; Z = X@W; sequential deflation collapses
// to 17-dim recurrences on the Gram of [Y|Z|1]; Out = Z - [Y|1]@Wmat.
// Structure (R18 = R14 restored; best verified 146.3us): 3 launches.
// kA: stats partials + zero gram/counter. kB: R11 GEMM geometry (2048 blocks
// = 32dg x 64rg, 8 blocks/CU -- R13 proved geometry is load-bearing).
// kCE: kC+kE fused ATOMICS-ONLY at SMALL scale: per-block ypart reduce for
// OWN 64 rows into LDS, gram via device-scope atomicAdd, 64-block counter
// spin, solve via relaxed agent atomic loads.
// WHY NO FURTHER FUSION (proven on-chip, 3 ways):
//  R12: __threadfence release = buffer_wbl2/inv per block -> +313us.
//  R15/16: 2048-wide spin kAB -> ~255us (pipes idle).
//  R17: bulk 8B atomic-store/load ypart (16.8MB) -> WRITE_SIZE 4x (66MB),
//       ~27ns/coherent-point-op serialization -> kBCE 130us. Bulk data
//       REQUIRES the kernel-boundary flush; atomics only for <=100KB.
// Floor audit: kA 11us (80% BW roofline), kB 14 (84MB HBM floor 13.3),
// kCE 6, gaps 12, harness fixed ~103 -> composed ~146 = measured. Input
// double-read irreducible: R = in.diag(inv).Wcat, diag inside contraction.
// Journal: R3 coop no-op. R7 readfirstlane weight s_load. R13 16-dgroup
// FAIL (occupancy). R14 kCE fuse WIN.

#define BB 4096
#define DD 4096
#define EPSF 1e-6f

// ws layout (float indices)
#define O_PART    0u          // [16 rowgroups][8192]: colsum(0..4095), colsq(4096..8191)
#define O_GRAMM   131072u     // 8 copies x 1120 (33x33, upper-tri used)
#define O_CNT     140032u     // 1 uint32 arrival counter (zeroed by kA)
#define O_YPART   271360u     // [32 dgroups][4096][32] (16B-aligned)

__device__ __forceinline__ int gidx(int a, int b) {   // upper-tri gram index
    int lo = a < b ? a : b, hi = a < b ? b : a;
    return lo * 33 + hi;
}

__device__ __forceinline__ float agl(const float* p) { // coherent-point load
    unsigned int u = __hip_atomic_load((const unsigned int*)p,
                                       __ATOMIC_RELAXED, __HIP_MEMORY_SCOPE_AGENT);
    return __uint_as_float(u);
}

// ============ kA: stats partials (16 rowgroups) + zero gram/counter =========
// 512 blocks = 32 colgroups(128 cols) x 16 rowgroups(256 rows).
__global__ __launch_bounds__(256, 2)
void kA(const float* __restrict__ in, float* __restrict__ ws) {
    __shared__ float rs[8 * 132], rq[8 * 132];        // pad 132: avoid 8-way bank hits
    int b = blockIdx.x, t = threadIdx.x;
    int idx = b * 256 + t;
    if (idx < 8961) ws[O_GRAMM + idx] = 0.f;          // 8 gram copies + counter
    int cg = b & 31, rg = b >> 5;
    int dbase = cg * 128, r0 = rg * 256;
    int chunk = t & 31, rr = t >> 5;
    int c0 = dbase + chunk * 4;
    float s0=0.f,s1=0.f,s2=0.f,s3=0.f,q0=0.f,q1=0.f,q2=0.f,q3=0.f;
    #pragma unroll 4
    for (int i = 0; i < 32; ++i) {
        int r = r0 + i * 8 + rr;
        float4 u = *(const float4*)&in[(size_t)r * DD + c0];
        s0 += u.x; q0 += u.x*u.x;  s1 += u.y; q1 += u.y*u.y;
        s2 += u.z; q2 += u.z*u.z;  s3 += u.w; q3 += u.w*u.w;
    }
    int lb = rr * 132 + chunk * 4;
    rs[lb+0]=s0; rs[lb+1]=s1; rs[lb+2]=s2; rs[lb+3]=s3;
    rq[lb+0]=q0; rq[lb+1]=q1; rq[lb+2]=q2; rq[lb+3]=q3;
    __syncthreads();
    float* part = ws + O_PART + (size_t)rg * 8192;
    if (t < 128) {                                    // finalize sums
        float a = 0.f;
        #pragma unroll
        for (int r2 = 0; r2 < 8; ++r2) a += rs[r2 * 132 + t];
        part[dbase + t] = a;
    } else {                                          // finalize sumsqs
        int ci = t - 128;
        float a = 0.f;
        #pragma unroll
        for (int r2 = 0; r2 < 8; ++r2) a += rq[r2 * 132 + ci];
        part[4096 + dbase + ci] = a;
    }
}

// ============ kB: inv-prologue + pure GEMM R = (in.inv) @ Wcat ==============
// 2048 blocks = 32 dgroups(128 d) x 64 rowgroups(64 rows). 8 blocks/CU.
// Thread: row = t&63, jq = readfirstlane(t>>6) -> j in [jq*8, jq*8+8).
__global__ __launch_bounds__(256, 8)
void kB(const float* __restrict__ in, const float* __restrict__ W,
        const float* __restrict__ Wstat, float* __restrict__ ws,
        float* __restrict__ ypart) {
    __shared__ __align__(16) float tile[64 * 33];     // 8.4 KB
    __shared__ __align__(16) float inv_s[128];
    int b = blockIdx.x, t = threadIdx.x;
    int dg = b & 31, rg = b >> 5;
    int dbase = dg * 128, rowbase = rg * 64;
    int chunk = t & 7, srow = t >> 3;                 // staging role (srow<32)
    int row = t & 63;
    int jq = __builtin_amdgcn_readfirstlane(t >> 6);  // wave-uniform -> s_load
    const float* inp = in + (size_t)(rowbase + srow) * DD + dbase + chunk * 4;
    float4 pf0 = *(const float4*)(inp);               // prefetch overlaps prologue
    float4 pf1 = *(const float4*)(inp + (size_t)32 * DD);
    {   // prologue: inv for this block's 128 cols from 16 KB L2-hot partials
        if (t < 128) {
            const float* part = ws + O_PART;
            float s = 0.f, q = 0.f;
            #pragma unroll
            for (int g = 0; g < 16; ++g) {
                s += part[(size_t)g * 8192 + dbase + t];
                q += part[(size_t)g * 8192 + 4096 + dbase + t];
            }
            float m = s * (1.0f / BB);
            float var = q * (1.0f / BB) - m * m; if (var < 0.f) var = 0.f;
            inv_s[t] = 1.0f / (sqrtf(var) + EPSF);
        }
        __syncthreads();
    }
    float acc[8];
    #pragma unroll
    for (int i = 0; i < 8; ++i) acc[i] = 0.f;
    // raw weight base: wave-uniform jq -> scalar loads (R7 lesson)
    const float* wbase = (jq < 2) ? (Wstat + jq * 8) : (W + (jq - 2) * 8);
    for (int stage = 0; stage < 4; ++stage) {
        int ds0 = stage * 32;
        float4 iv4 = *(const float4*)&inv_s[ds0 + chunk * 4];
        int b0 = srow * 33 + chunk * 4;               // scale folded into staging
        tile[b0 + 0] = pf0.x * iv4.x; tile[b0 + 1] = pf0.y * iv4.y;
        tile[b0 + 2] = pf0.z * iv4.z; tile[b0 + 3] = pf0.w * iv4.w;
        int b1 = (srow + 32) * 33 + chunk * 4;
        tile[b1 + 0] = pf1.x * iv4.x; tile[b1 + 1] = pf1.y * iv4.y;
        tile[b1 + 2] = pf1.z * iv4.z; tile[b1 + 3] = pf1.w * iv4.w;
        __syncthreads();
        if (stage < 3) {                              // prefetch next stage
            pf0 = *(const float4*)(inp + (stage + 1) * 32);
            pf1 = *(const float4*)(inp + (size_t)32 * DD + (stage + 1) * 32);
        }
        const float* trow = tile + row * 33;
        #pragma unroll 4
        for (int dl = 0; dl < 32; ++dl) {
            float xs = trow[dl];
            const float* wr = wbase + (size_t)(dbase + ds0 + dl) * 16;
            #pragma unroll
            for (int j = 0; j < 8; ++j) acc[j] += xs * wr[j];
        }
        __syncthreads();
    }
    float* dst = ypart + ((size_t)dg * BB + rowbase + row) * 32 + jq * 8;
    *(float4*)(dst + 0) = make_float4(acc[0], acc[1], acc[2], acc[3]);
    *(float4*)(dst + 4) = make_float4(acc[4], acc[5], acc[6], acc[7]);
}

// ====== kCE: per-block ypart reduce + gram atomics + spin + solve ===========
// 64 blocks x 512 threads, all co-resident (64 <= 256 CUs). Atomics-only
// cross-block communication at SMALL scale; no global yz; no fences.
__global__ __launch_bounds__(512, 1)
void kCE(float* __restrict__ ws, float* __restrict__ out) {
    __shared__ __align__(16) float yzs[64 * 36];      // own 64 rows of [Ry|Rz|1]
    __shared__ float Sv[33], GA[17 * 17], gz[17 * 16], v[15][17], gad[15][16],
                     gzd[15][16], gu[17], u[17], st[2], wm[17 * 16];
    int b = blockIdx.x, t = threadIdx.x;
    int rowbase = b * 64;
    const float invB = 1.0f / BB;

    // phase 1: reduce 32 dgroup planes for own rows -> LDS (no global write)
    {
        int r = t >> 3, q = (t & 7) * 4;              // 512 threads = 64 rows x 8 quads
        const float* yp = ws + O_YPART;
        size_t off = (size_t)(rowbase + r) * 32 + q;
        float x0=0.f, x1=0.f, x2=0.f, x3=0.f;
        #pragma unroll 8
        for (int dg = 0; dg < 32; ++dg) {
            float4 vv = *(const float4*)&yp[(size_t)dg * (BB * 32) + off];
            x0 += vv.x; x1 += vv.y; x2 += vv.z; x3 += vv.w;
        }
        int lb = r * 36 + q;
        yzs[lb + 0] = x0; yzs[lb + 1] = x1; yzs[lb + 2] = x2; yzs[lb + 3] = x3;
        if (q == 0) yzs[r * 36 + 32] = 1.0f;          // ones column
    }
    __syncthreads();

    // phase 2: gram contribution for own 64 rows (8-way copies by b&7)
    float* gm8 = ws + O_GRAMM + (size_t)(b & 7) * 1120;
    for (int p = t; p < 561; p += 512) {              // upper-tri pairs i<=j<=32
        int i = 0, rem = p;
        while (rem >= 33 - i) { rem -= 33 - i; ++i; }
        int j = i + rem;
        float a2 = 0.f;
        #pragma unroll 8
        for (int r2 = 0; r2 < 64; ++r2)
            a2 += yzs[r2 * 36 + i] * yzs[r2 * 36 + j];
        atomicAdd(&gm8[i * 33 + j], a2);
    }

    // phase 3: arrival + spin. syncthreads drains vmcnt -> this block's gram
    // atomics are at the coherent point before the counter bump (release).
    __syncthreads();
    unsigned int* cnt = (unsigned int*)(ws + O_CNT);
    if (t == 0) {
        atomicAdd(cnt, 1u);
        while (__hip_atomic_load(cnt, __ATOMIC_RELAXED,
                                 __HIP_MEMORY_SCOPE_AGENT) < 64u)
            __builtin_amdgcn_s_sleep(8);
    }
    __syncthreads();

    // phase 4: solve, reading gram ONLY via coherent-point atomic loads
    const float* gm = ws + O_GRAMM;
    if (t < 33) {                                     // S_i = <R_i, 1> (i=32: B)
        float s = 0.f;
        #pragma unroll
        for (int m = 0; m < 8; ++m) s += agl(&gm[m * 1120 + gidx(t, 32)]);
        Sv[t] = s;
    }
    __syncthreads();
    for (int idx = t; idx < 17 * 17; idx += 512) {    // centered GA
        int p = idx / 17, q = idx % 17;
        float val;
        if (p < 16 && q < 16) {
            float raw = 0.f;
            #pragma unroll
            for (int m = 0; m < 8; ++m) raw += agl(&gm[m * 1120 + gidx(p, q)]);
            val = raw - Sv[p] * Sv[q] * invB;
        } else if (p == 16 && q == 16) val = (float)BB;
        else val = 0.f;                               // <P,1> = 0 exactly
        GA[idx] = val;
    }
    for (int idx = t; idx < 17 * 16; idx += 512) {    // centered gz
        int p = idx / 16, tt = idx % 16;
        float val = 0.f;
        if (p < 16) {
            float raw = 0.f;
            #pragma unroll
            for (int m = 0; m < 8; ++m) raw += agl(&gm[m * 1120 + gidx(p, 16 + tt)]);
            val = raw - Sv[p] * Sv[16 + tt] * invB;
        }
        gz[idx] = val;
    }
    if (t < 17) u[t] = (t == 0) ? 1.f : 0.f;
    __syncthreads();
    for (int i = 0; i < 15; ++i) {
        if (t < 17) {                                 // gu = GA @ u
            float s = 0.f;
            for (int q = 0; q < 17; ++q) s += GA[t * 17 + q] * u[q];
            gu[t] = s;
        }
        __syncthreads();
        if (t == 0) {                                 // stats of c_i
            float mean = gu[16] * invB, e2 = 0.f;
            for (int p = 0; p < 17; ++p) e2 += u[p] * gu[p];
            e2 *= invB;
            float var = e2 - mean * mean; if (var < 0.f) var = 0.f;
            st[0] = mean; st[1] = 1.0f / (sqrtf(var) + EPSF);
        }
        __syncthreads();
        if (t < 17) v[i][t] = (u[t] - (t == 16 ? st[0] : 0.f)) * st[1];
        __syncthreads();
        if (t < 16) {                                 // conv_i . Y[:,k]
            float s = 0.f;
            for (int p = 0; p < 17; ++p) s += v[i][p] * GA[p * 17 + t];
            gad[i][t] = s;
        } else if (t < 32) {                          // conv_i . Z[:,tt]
            int tt = t - 16;
            float s = 0.f;
            for (int p = 0; p < 17; ++p) s += v[i][p] * gz[p * 16 + tt];
            gzd[i][tt] = s;
        }
        __syncthreads();
        if (t < 17) {                                 // u_{i+1}
            float a2 = 0.f;
            for (int j = 0; j <= i; ++j) a2 += v[j][t] * gad[j][i + 1];
            u[t] = ((t == i + 1) ? 1.f : 0.f) - a2 * invB;
        }
        __syncthreads();
    }
    for (int idx = t; idx < 17 * 16; idx += 512) {
        int p = idx / 16, tt = idx % 16;
        float s = 0.f;
        for (int j = 0; j < tt; ++j) s += v[j][p] * gzd[j][tt];
        wm[idx] = s * invB;
    }
    __syncthreads();
    if (t < 16) {                                     // fold shifts into ones-row
        float adj = Sv[16 + t] * invB;
        for (int p = 0; p < 16; ++p) adj -= Sv[p] * invB * wm[p * 16 + t];
        wm[16 * 16 + t] += adj;
    }
    __syncthreads();
    if (t < 256) {                                    // epilogue: own 64 rows
        int row = t >> 2, c0 = (t & 3) * 4;
        const float* yr = yzs + row * 36;
        float o[4];
        #pragma unroll
        for (int k = 0; k < 4; ++k) o[k] = yr[16 + c0 + k] - wm[16 * 16 + c0 + k];
        #pragma unroll
        for (int p = 0; p < 16; ++p) {
            float yp = yr[p];
            #pragma unroll
            for (int k = 0; k < 4; ++k) o[k] -= yp * wm[p * 16 + c0 + k];
        }
        *(float4*)&out[(size_t)rowbase * 16 + t * 4] = make_float4(o[0], o[1], o[2], o[3]);
    }
}

extern "C" void kernel_launch(void* const* d_in, const int* in_sizes, int n_in,
                              void* d_out, int out_size, void* d_ws, size_t ws_size,
                              hipStream_t stream) {
    const float* in    = (const float*)d_in[0];
    const float* W     = (const float*)d_in[1];
    const float* Wstat = (const float*)d_in[2];
    float* ws  = (float*)d_ws;
    float* out = (float*)d_out;

    kA<<<dim3(512),  dim3(256), 0, stream>>>(in, ws);
    kB<<<dim3(2048), dim3(256), 0, stream>>>(in, W, Wstat, ws, ws + O_YPART);
    kCE<<<dim3(64),  dim3(512), 0, stream>>>(ws, out);
}